// Round 1
// baseline (627.632 us; speedup 1.0000x reference)
//
#include <hip/hip_runtime.h>

// Problem constants (fixed in reference file): N=1, C=128, H=W=512, p=2
#define HW (512 * 512)     // 262144 pixels per channel plane
#define NC 128             // total channels
#define CH 64              // channels per conv (= C/2 = number of even channels)

// ---------------------------------------------------------------------------
// Even channels: out_lst[2k] = sum_c w2[k][c]*gui[2c] + b2[k]
//                out_gui[2k] = sum_c w1[k][c]*lst[2c] + b1[k]
// One pixel per thread. Input channel values cached in 64 VGPRs; weights are
// indexed wave-uniformly -> scalar loads through the constant cache.
// ---------------------------------------------------------------------------
__global__ __launch_bounds__(256) void conv_even_kernel(
    const float* __restrict__ lst, const float* __restrict__ gui,
    const float* __restrict__ w1, const float* __restrict__ b1,
    const float* __restrict__ w2, const float* __restrict__ b2,
    float* __restrict__ out_lst, float* __restrict__ out_gui)
{
    const int pix = blockIdx.x * 256 + threadIdx.x;  // 0 .. HW-1 exactly

    float x[CH];

    // ---- conv2(gui_even) -> out_lst even channels ----
    #pragma unroll
    for (int c = 0; c < CH; ++c) x[c] = gui[(2 * c) * HW + pix];

    for (int k = 0; k < CH; ++k) {
        float acc = b2[k];
        #pragma unroll
        for (int c = 0; c < CH; ++c) acc = fmaf(w2[k * CH + c], x[c], acc);
        out_lst[(2 * k) * HW + pix] = acc;
    }

    // ---- conv1(lst_even) -> out_gui even channels ----
    #pragma unroll
    for (int c = 0; c < CH; ++c) x[c] = lst[(2 * c) * HW + pix];

    for (int k = 0; k < CH; ++k) {
        float acc = b1[k];
        #pragma unroll
        for (int c = 0; c < CH; ++c) acc = fmaf(w1[k * CH + c], x[c], acc);
        out_gui[(2 * k) * HW + pix] = acc;
    }
}

// ---------------------------------------------------------------------------
// Odd channels: straight passthrough copy, float4-vectorized.
// i -> odd plane c (i >> 16) and float4 offset within plane (i & 0xFFFF);
// HW/4 = 65536 float4 per plane (power of two -> shifts only).
// ---------------------------------------------------------------------------
__global__ __launch_bounds__(256) void copy_odd_kernel(
    const float4* __restrict__ lst, const float4* __restrict__ gui,
    float4* __restrict__ out_lst, float4* __restrict__ out_gui)
{
    const int i = blockIdx.x * 256 + threadIdx.x;   // 0 .. 64*65536-1
    const int c = i >> 16;                          // odd-plane index 0..63
    const int j = i & 0xFFFF;                       // float4 within plane
    const int off = ((2 * c + 1) << 16) + j;        // plane (2c+1), float4 units

    out_lst[off] = lst[off];
    out_gui[off] = gui[off];
}

extern "C" void kernel_launch(void* const* d_in, const int* in_sizes, int n_in,
                              void* d_out, int out_size, void* d_ws, size_t ws_size,
                              hipStream_t stream) {
    const float* lst = (const float*)d_in[0];
    const float* gui = (const float*)d_in[1];
    const float* w1  = (const float*)d_in[2];
    const float* b1  = (const float*)d_in[3];
    const float* w2  = (const float*)d_in[4];
    const float* b2  = (const float*)d_in[5];
    // d_in[6] is p; fixed at 2 for this problem.

    float* out_lst = (float*)d_out;                      // first tuple element
    float* out_gui = out_lst + (size_t)NC * HW;          // second tuple element

    // Even channels (conv): 262144 pixels / 256 threads = 1024 blocks.
    conv_even_kernel<<<HW / 256, 256, 0, stream>>>(lst, gui, w1, b1, w2, b2,
                                                   out_lst, out_gui);

    // Odd channels (copy): 64 planes * 65536 float4 = 4,194,304 / 256 = 16384 blocks.
    copy_odd_kernel<<<(64 * (HW / 4)) / 256, 256, 0, stream>>>(
        (const float4*)lst, (const float4*)gui, (float4*)out_lst, (float4*)out_gui);
}

// Round 2
// 552.565 us; speedup vs baseline: 1.1359x; 1.1359x over previous
//
#include <hip/hip_runtime.h>

// Problem constants (fixed): N=1, C=128, H=W=512, p=2
#define HW (512 * 512)       // 262144 pixels per plane
#define CH 64                // channels per conv
#define CONV_BLOCKS 1024     // HW / 256 pixels-per-block
#define COPY_BLOCKS 4096
#define COPY_THREADS (COPY_BLOCKS * 256)   // 1,048,576
#define COPY_R 4             // float4 per tensor per copy thread (4 * 1M = 4M = all odd float4s)

// One fused kernel, block-role split:
//   blocks [0, 1024):        conv role — 1 pixel/thread, c-chunked GEMV with 64
//                            live accumulators (loads spread across compute).
//   blocks [1024, 5120):     copy role — odd-channel passthrough, float4.
// Roles write disjoint planes (even vs odd), so no ordering needed. Fusing lets
// the BW-bound copy waves overlap the VALU/latency-bound conv waves.
__global__ __launch_bounds__(256) void fused_exchange_kernel(
    const float* __restrict__ lst, const float* __restrict__ gui,
    const float* __restrict__ w1, const float* __restrict__ b1,
    const float* __restrict__ w2, const float* __restrict__ b2,
    float* __restrict__ out_lst, float* __restrict__ out_gui)
{
    const int b = blockIdx.x;

    if (b < CONV_BLOCKS) {
        const int pix = b * 256 + threadIdx.x;   // 0 .. HW-1 exactly

        // ---------- pass 1: out_lst[2k] = sum_c w2[k][c]*gui[2c] + b2[k] ----------
        {
            float acc[CH];
            #pragma unroll
            for (int k = 0; k < CH; ++k) acc[k] = b2[k];

            for (int cc = 0; cc < CH; cc += 8) {          // 8 c-chunks
                float x[8];
                #pragma unroll
                for (int j = 0; j < 8; ++j)
                    x[j] = gui[(size_t)(2 * (cc + j)) * HW + pix];
                #pragma unroll
                for (int k = 0; k < CH; ++k) {            // k fully unrolled: s_loads pipeline
                    const float* wr = w2 + k * CH + cc;   // wave-uniform -> s_load_dwordx8
                    float a = acc[k];
                    a = fmaf(wr[0], x[0], a);
                    a = fmaf(wr[1], x[1], a);
                    a = fmaf(wr[2], x[2], a);
                    a = fmaf(wr[3], x[3], a);
                    a = fmaf(wr[4], x[4], a);
                    a = fmaf(wr[5], x[5], a);
                    a = fmaf(wr[6], x[6], a);
                    a = fmaf(wr[7], x[7], a);
                    acc[k] = a;
                }
            }
            #pragma unroll
            for (int k = 0; k < CH; ++k)
                out_lst[(size_t)(2 * k) * HW + pix] = acc[k];
        }

        // ---------- pass 2: out_gui[2k] = sum_c w1[k][c]*lst[2c] + b1[k] ----------
        {
            float acc[CH];
            #pragma unroll
            for (int k = 0; k < CH; ++k) acc[k] = b1[k];

            for (int cc = 0; cc < CH; cc += 8) {
                float x[8];
                #pragma unroll
                for (int j = 0; j < 8; ++j)
                    x[j] = lst[(size_t)(2 * (cc + j)) * HW + pix];
                #pragma unroll
                for (int k = 0; k < CH; ++k) {
                    const float* wr = w1 + k * CH + cc;
                    float a = acc[k];
                    a = fmaf(wr[0], x[0], a);
                    a = fmaf(wr[1], x[1], a);
                    a = fmaf(wr[2], x[2], a);
                    a = fmaf(wr[3], x[3], a);
                    a = fmaf(wr[4], x[4], a);
                    a = fmaf(wr[5], x[5], a);
                    a = fmaf(wr[6], x[6], a);
                    a = fmaf(wr[7], x[7], a);
                    acc[k] = a;
                }
            }
            #pragma unroll
            for (int k = 0; k < CH; ++k)
                out_gui[(size_t)(2 * k) * HW + pix] = acc[k];
        }
    } else {
        // ---------- copy role: odd planes, float4 ----------
        const int t = (b - CONV_BLOCKS) * 256 + threadIdx.x;  // 0 .. 1M-1
        const float4* l4  = (const float4*)lst;
        const float4* g4  = (const float4*)gui;
        float4* ol4 = (float4*)out_lst;
        float4* og4 = (float4*)out_gui;

        #pragma unroll
        for (int r = 0; r < COPY_R; ++r) {
            const int idx = t + r * COPY_THREADS;   // 0 .. 4M-1, dense
            const int c   = idx >> 16;              // odd-plane index 0..63
            const int j   = idx & 0xFFFF;           // float4 within plane (HW/4 = 65536)
            const int off = ((2 * c + 1) << 16) + j;
            ol4[off] = l4[off];
            og4[off] = g4[off];
        }
    }
}

extern "C" void kernel_launch(void* const* d_in, const int* in_sizes, int n_in,
                              void* d_out, int out_size, void* d_ws, size_t ws_size,
                              hipStream_t stream) {
    const float* lst = (const float*)d_in[0];
    const float* gui = (const float*)d_in[1];
    const float* w1  = (const float*)d_in[2];
    const float* b1  = (const float*)d_in[3];
    const float* w2  = (const float*)d_in[4];
    const float* b2  = (const float*)d_in[5];
    // d_in[6] is p; fixed at 2.

    float* out_lst = (float*)d_out;
    float* out_gui = out_lst + (size_t)128 * HW;

    fused_exchange_kernel<<<CONV_BLOCKS + COPY_BLOCKS, 256, 0, stream>>>(
        lst, gui, w1, b1, w2, b2, out_lst, out_gui);
}